// Round 5
// baseline (71.645 us; speedup 1.0000x reference)
//
#include <hip/hip_runtime.h>
#include <math.h>

#define IMG 256
#define NFACE 1000
#define NCHUNK 8
#define FPC (NFACE / NCHUNK)   // 125 faces per chunk
#define EPSF 1e-8f
#define LOG2E 1.44269504088896f
#define TCUT 16.0f             // drop contributions with u < -TCUT (<= 1.44*2^-16 each)
#define TBAND 11.1f            // TCUT / log2(e), pixel-space band half-width
#define ACC_BREAK 25.0f        // once all lanes exceed: sil error < 2^-25

struct __align__(16) FaceRec {
    int4 bb;            // xmin, ymin, xmax, ymax (conservative)
    float4 e0, e1, e2;  // per edge: (cx, cy, c0, pad), pre-scaled by log2(e)
};

// Static device scratch (graph-capture safe).
__device__ FaceRec g_face[NFACE];
__device__ float g_partial[NCHUNK * IMG * IMG];

// ---------------------------------------------------------------------------
// Kernel 1: per-face edge coefficients + conservative bbox of {d >= -TBAND}
// (exact construction via shifted-edge intersection points). Degenerate faces
// (zero-length projected edge: c==0 everywhere, face paints an infinite line
// band) get a full-image bbox - never culled.
// ---------------------------------------------------------------------------
__global__ __launch_bounds__(256) void k_coeff(const float* __restrict__ verts,
                                               const int* __restrict__ faces,
                                               const float* __restrict__ q,
                                               const float* __restrict__ t,
                                               const float* __restrict__ K) {
    int f = blockIdx.x * blockDim.x + threadIdx.x;
    if (f >= NFACE) return;

    float qw = q[0], qx = q[1], qy = q[2], qz = q[3];
    float qn = sqrtf(qw * qw + qx * qx + qy * qy + qz * qz + EPSF);
    qw /= qn; qx /= qn; qy /= qn; qz /= qn;
    float R00 = 1.f - 2.f * (qy * qy + qz * qz);
    float R01 = 2.f * (qx * qy - qw * qz);
    float R02 = 2.f * (qx * qz + qw * qy);
    float R10 = 2.f * (qx * qy + qw * qz);
    float R11 = 1.f - 2.f * (qx * qx + qz * qz);
    float R12 = 2.f * (qy * qz - qw * qx);
    float R20 = 2.f * (qx * qz - qw * qy);
    float R21 = 2.f * (qy * qz + qw * qx);
    float R22 = 1.f - 2.f * (qx * qx + qy * qy);
    float tx = t[0], ty = t[1], tz = t[2];
    float K00 = K[0], K02 = K[2], K11 = K[4], K12 = K[5];

    float X[3], Y[3];
#pragma unroll
    for (int k = 0; k < 3; ++k) {
        int vi = faces[f * 3 + k];
        float vx = verts[vi * 3 + 0];
        float vy = verts[vi * 3 + 1];
        float vz = verts[vi * 3 + 2];
        float cx = R00 * vx + R01 * vy + R02 * vz + tx;
        float cy = R10 * vx + R11 * vy + R12 * vz + ty;
        float cz = R20 * vx + R21 * vy + R22 * vz + tz;
        float z = cz + EPSF;
        X[k] = K00 * cx / z + K02;
        Y[k] = K11 * cy / z + K12;
    }

    float e01x = X[1] - X[0], e01y = Y[1] - Y[0];
    float e02x = X[2] - X[0], e02y = Y[2] - Y[0];
    float area2 = e01x * e02y - e01y * e02x;
    float s = (area2 >= 0.f) ? 1.f : -1.f;

    float ucx[3], ucy[3], uc0[3];
    bool degen = false;
#pragma unroll
    for (int k = 0; k < 3; ++k) {
        int k1 = (k + 1) % 3;
        float ex = X[k1] - X[k];
        float ey = Y[k1] - Y[k];
        float l2 = ex * ex + ey * ey;
        degen = degen || (l2 < 1e-6f);
        float inv = s / sqrtf(l2 + EPSF);
        ucx[k] = -ey * inv;
        ucy[k] = ex * inv;
        uc0[k] = (ey * X[k] - ex * Y[k]) * inv;
    }

    int4 bbi;
    if (degen) {
        bbi = make_int4(0, 0, IMG - 1, IMG - 1);
    } else {
        float xmn = 1e9f, xmx = -1e9f, ymn = 1e9f, ymx = -1e9f;
#pragma unroll
        for (int k = 0; k < 3; ++k) {
            int i = (k + 2) % 3, j = k;
            float dt = ucx[i] * ucx[j] + ucy[i] * ucy[j];
            float w = TBAND / fmaxf(1.f + dt, 1e-4f);
            float Px = X[k] - (ucx[i] + ucx[j]) * w;
            float Py = Y[k] - (ucy[i] + ucy[j]) * w;
            Px = fminf(fmaxf(Px, -2e4f), 2e4f);
            Py = fminf(fmaxf(Py, -2e4f), 2e4f);
            xmn = fminf(xmn, Px); xmx = fmaxf(xmx, Px);
            ymn = fminf(ymn, Py); ymx = fmaxf(ymx, Py);
        }
        bbi = make_int4((int)floorf(xmn) - 1, (int)floorf(ymn) - 1,
                        (int)ceilf(xmx) + 1, (int)ceilf(ymx) + 1);
    }

    FaceRec r;
    r.bb = bbi;
    r.e0 = make_float4(ucx[0] * LOG2E, ucy[0] * LOG2E, uc0[0] * LOG2E, 0.f);
    r.e1 = make_float4(ucx[1] * LOG2E, ucy[1] * LOG2E, uc0[1] * LOG2E, 0.f);
    r.e2 = make_float4(ucx[2] * LOG2E, ucy[2] * LOG2E, uc0[2] * LOG2E, 0.f);
    g_face[f] = r;
}

// ---------------------------------------------------------------------------
// Kernel 2: heavy pass. bid -> (chunk = bid&7, row = bid>>3) so each CU's
// resident blocks span rows 32 apart (load balance). Wave = 64px row segment.
// Three exact-conservative cuts:
//   (1) bbox reject (cheap, kills background)
//   (2) per-edge segment-endpoint reject (kills sliver-bbox dead space):
//       c_k is linear in x on the segment; if max over endpoints < -TCUT for
//       any edge, every lane has u < -TCUT -> contribution < 1.44*2^-16.
//   (3) early break once __all(acc > 25): contributions are >= 0, so the
//       remaining faces change sil by < 2^-25 (interior pixels).
// ---------------------------------------------------------------------------
__global__ __launch_bounds__(256) void k_partial() {
    const int bid = blockIdx.x;
    const int chunk = bid & (NCHUNK - 1);
    const int row = bid >> 3;
    const int col = threadIdx.x;
    const float px = col + 0.5f;
    const float py = row + 0.5f;
    const int xlo = col & 192;         // wave-uniform segment start
    const int xhi = xlo + 63;
    const float pxlo = xlo + 0.5f;
    const float pxhi = xlo + 63.5f;

    const FaceRec* __restrict__ fc = &g_face[chunk * FPC];

    float acc = 0.f;
    for (int f = 0; f < FPC; ++f) {
        int4 bb = fc[f].bb;
        bool rej = (row < bb.y) | (row > bb.w) | (xhi < bb.x) | (xlo > bb.z);
        if (__all(rej)) continue;

        float4 a = fc[f].e0;
        float4 b = fc[f].e1;
        float4 c = fc[f].e2;
        float bA = fmaf(py, a.y, a.z);
        float bB = fmaf(py, b.y, b.z);
        float bC = fmaf(py, c.y, c.z);

        float mA = fmaxf(fmaf(pxlo, a.x, bA), fmaf(pxhi, a.x, bA));
        float mB = fmaxf(fmaf(pxlo, b.x, bB), fmaf(pxhi, b.x, bB));
        float mC = fmaxf(fmaf(pxlo, c.x, bC), fmaf(pxhi, c.x, bC));
        if (fminf(fminf(mA, mB), mC) < -TCUT) continue;  // uniform-valued

        float u = fminf(fminf(fmaf(px, a.x, bA), fmaf(px, b.x, bB)),
                        fmaf(px, c.x, bC));
        acc += fmaxf(u, 0.f);
        if (__any(fabsf(u) < TCUT)) {
            acc += __builtin_amdgcn_logf(1.f + __builtin_amdgcn_exp2f(-fabsf(u)));
        }
        if (__all(acc > ACC_BREAK)) break;
    }
    g_partial[chunk * (IMG * IMG) + row * IMG + col] = acc;
}

// ---------------------------------------------------------------------------
// Kernel 3: combine chunks, silhouette, squared error, row-mean reduce.
// ---------------------------------------------------------------------------
__global__ __launch_bounds__(256) void k_final(const float* __restrict__ image_ref,
                                               float* __restrict__ out) {
    const int row = blockIdx.x;
    const int col = threadIdx.x;
    const int pix = row * IMG + col;

    float ssum = 0.f;
#pragma unroll
    for (int c = 0; c < NCHUNK; ++c) ssum += g_partial[c * (IMG * IMG) + pix];

    float sil = 1.f - __builtin_amdgcn_exp2f(-ssum);
    float diff = sil - image_ref[pix];
    float v = diff * diff;

#pragma unroll
    for (int o = 32; o > 0; o >>= 1) v += __shfl_down(v, o);

    __shared__ float wsum[4];
    if ((col & 63) == 0) wsum[col >> 6] = v;
    __syncthreads();
    if (col == 0) {
        out[row] = (wsum[0] + wsum[1] + wsum[2] + wsum[3]) * (1.f / 256.f);
    }
}

// ---------------------------------------------------------------------------
extern "C" void kernel_launch(void* const* d_in, const int* in_sizes, int n_in,
                              void* d_out, int out_size, void* d_ws, size_t ws_size,
                              hipStream_t stream) {
    const float* verts = (const float*)d_in[0];      // (1,1000,3) f32
    const int* faces = (const int*)d_in[1];          // (1,1000,3) i32
    const float* q = (const float*)d_in[2];          // (4,) f32
    const float* t = (const float*)d_in[3];          // (3,) f32
    const float* K = (const float*)d_in[4];          // (3,3) f32
    const float* image_ref = (const float*)d_in[5];  // (256,256) f32
    float* out = (float*)d_out;                      // (256,) f32

    k_coeff<<<(NFACE + 255) / 256, 256, 0, stream>>>(verts, faces, q, t, K);
    k_partial<<<IMG * NCHUNK, 256, 0, stream>>>();
    k_final<<<IMG, 256, 0, stream>>>(image_ref, out);
}

// Round 6
// 44.547 us; speedup vs baseline: 1.6083x; 1.6083x over previous
//
#include <hip/hip_runtime.h>
#include <math.h>

#define IMG 256
#define NFACE 1000
#define NCHUNK 8
#define FPC (NFACE / NCHUNK)   // 125 faces per chunk
#define EPSF 1e-8f
#define LOG2E 1.44269504088896f
#define TCUT 16.0f             // drop contributions with u < -TCUT (<= 1.44*2^-16 each)
#define TBAND 11.1f            // TCUT / log2(e), pixel-space band half-width
#define ACC_BREAK 25.0f        // once all lanes exceed: sil error < 2^-25

struct __align__(16) FaceRec {
    int4 bb;            // xmin, ymin, xmax, ymax (conservative)
    float4 e0, e1, e2;  // per edge: (cx, cy, c0, pad), pre-scaled by log2(e)
};

// Static device scratch (graph-capture safe).
__device__ FaceRec g_face[NFACE];
__device__ float g_partial[NCHUNK * IMG * IMG];

// ---------------------------------------------------------------------------
// Kernel 1: per-face edge coefficients + conservative bbox of {d >= -TBAND}
// (exact construction via shifted-edge intersection points). Degenerate faces
// (zero-length projected edge: c==0 everywhere, face paints an infinite line
// band) get a full-image bbox - never culled.
// ---------------------------------------------------------------------------
__global__ __launch_bounds__(256) void k_coeff(const float* __restrict__ verts,
                                               const int* __restrict__ faces,
                                               const float* __restrict__ q,
                                               const float* __restrict__ t,
                                               const float* __restrict__ K) {
    int f = blockIdx.x * blockDim.x + threadIdx.x;
    if (f >= NFACE) return;

    float qw = q[0], qx = q[1], qy = q[2], qz = q[3];
    float qn = sqrtf(qw * qw + qx * qx + qy * qy + qz * qz + EPSF);
    qw /= qn; qx /= qn; qy /= qn; qz /= qn;
    float R00 = 1.f - 2.f * (qy * qy + qz * qz);
    float R01 = 2.f * (qx * qy - qw * qz);
    float R02 = 2.f * (qx * qz + qw * qy);
    float R10 = 2.f * (qx * qy + qw * qz);
    float R11 = 1.f - 2.f * (qx * qx + qz * qz);
    float R12 = 2.f * (qy * qz - qw * qx);
    float R20 = 2.f * (qx * qz - qw * qy);
    float R21 = 2.f * (qy * qz + qw * qx);
    float R22 = 1.f - 2.f * (qx * qx + qy * qy);
    float tx = t[0], ty = t[1], tz = t[2];
    float K00 = K[0], K02 = K[2], K11 = K[4], K12 = K[5];

    float X[3], Y[3];
#pragma unroll
    for (int k = 0; k < 3; ++k) {
        int vi = faces[f * 3 + k];
        float vx = verts[vi * 3 + 0];
        float vy = verts[vi * 3 + 1];
        float vz = verts[vi * 3 + 2];
        float cx = R00 * vx + R01 * vy + R02 * vz + tx;
        float cy = R10 * vx + R11 * vy + R12 * vz + ty;
        float cz = R20 * vx + R21 * vy + R22 * vz + tz;
        float z = cz + EPSF;
        X[k] = K00 * cx / z + K02;
        Y[k] = K11 * cy / z + K12;
    }

    float e01x = X[1] - X[0], e01y = Y[1] - Y[0];
    float e02x = X[2] - X[0], e02y = Y[2] - Y[0];
    float area2 = e01x * e02y - e01y * e02x;
    float s = (area2 >= 0.f) ? 1.f : -1.f;

    float ucx[3], ucy[3], uc0[3];
    bool degen = false;
#pragma unroll
    for (int k = 0; k < 3; ++k) {
        int k1 = (k + 1) % 3;
        float ex = X[k1] - X[k];
        float ey = Y[k1] - Y[k];
        float l2 = ex * ex + ey * ey;
        degen = degen || (l2 < 1e-6f);
        float inv = s / sqrtf(l2 + EPSF);
        ucx[k] = -ey * inv;
        ucy[k] = ex * inv;
        uc0[k] = (ey * X[k] - ex * Y[k]) * inv;
    }

    int4 bbi;
    if (degen) {
        bbi = make_int4(0, 0, IMG - 1, IMG - 1);
    } else {
        float xmn = 1e9f, xmx = -1e9f, ymn = 1e9f, ymx = -1e9f;
#pragma unroll
        for (int k = 0; k < 3; ++k) {
            int i = (k + 2) % 3, j = k;
            float dt = ucx[i] * ucx[j] + ucy[i] * ucy[j];
            float w = TBAND / fmaxf(1.f + dt, 1e-4f);
            float Px = X[k] - (ucx[i] + ucx[j]) * w;
            float Py = Y[k] - (ucy[i] + ucy[j]) * w;
            Px = fminf(fmaxf(Px, -2e4f), 2e4f);
            Py = fminf(fmaxf(Py, -2e4f), 2e4f);
            xmn = fminf(xmn, Px); xmx = fmaxf(xmx, Px);
            ymn = fminf(ymn, Py); ymx = fmaxf(ymx, Py);
        }
        bbi = make_int4((int)floorf(xmn) - 1, (int)floorf(ymn) - 1,
                        (int)ceilf(xmx) + 1, (int)ceilf(ymx) + 1);
    }

    FaceRec r;
    r.bb = bbi;
    r.e0 = make_float4(ucx[0] * LOG2E, ucy[0] * LOG2E, uc0[0] * LOG2E, 0.f);
    r.e1 = make_float4(ucx[1] * LOG2E, ucy[1] * LOG2E, uc0[1] * LOG2E, 0.f);
    r.e2 = make_float4(ucx[2] * LOG2E, ucy[2] * LOG2E, uc0[2] * LOG2E, 0.f);
    g_face[f] = r;
}

// ---------------------------------------------------------------------------
// Kernel 2: heavy pass, restructured for ILP (R5 post-mortem: branchy fused
// cull was latency-bound at VALUBusy 39%).
//   Stage:   chunk's 125 FaceRecs -> LDS (coop, once per block).
//   Phase A: parallel bbox cull - lane l tests face l vs the wave's 8x8 tile,
//            ballot + popc-prefix compaction into a per-wave survivor list.
//   Phase B: branch-light walk of survivors (uniform LDS broadcast reads,
//            2-face unroll), guarded trans, every-2-faces early break.
// Grid: (16,16,NCHUNK) blocks of 256; wave = 8x8 px sub-tile.
// ---------------------------------------------------------------------------
__global__ __launch_bounds__(256) void k_partial() {
    const int chunk = blockIdx.z;
    const int tid = threadIdx.x;
    const int wave = tid >> 6;
    const int lane = tid & 63;

    const int cx0 = blockIdx.x * 16 + (wave & 1) * 8;
    const int cy0 = blockIdx.y * 16 + (wave >> 1) * 8;
    const int col = cx0 + (lane & 7);
    const int row = cy0 + (lane >> 3);
    const float px = col + 0.5f;
    const float py = row + 0.5f;

    __shared__ int4 s_bb[FPC];
    __shared__ float4 s_cf[FPC * 3];
    __shared__ short s_list[4 * 128];

    // ---- stage chunk faces into LDS (dense, coalesced) ----
    const float4* __restrict__ src =
        reinterpret_cast<const float4*>(&g_face[chunk * FPC]);
    for (int j = tid; j < FPC * 4; j += 256) {
        float4 v = src[j];
        int f = j >> 2, p = j & 3;
        if (p == 0) {
            s_bb[f] = make_int4(__float_as_int(v.x), __float_as_int(v.y),
                                __float_as_int(v.z), __float_as_int(v.w));
        } else {
            s_cf[f * 3 + (p - 1)] = v;
        }
    }
    __syncthreads();

    // ---- Phase A: parallel cull + compaction (per wave) ----
    const int cx1 = cx0 + 7, cy1 = cy0 + 7;
    int cnt = 0;
    for (int base = 0; base < FPC; base += 64) {
        int f = base + lane;
        bool hit = false;
        if (f < FPC) {
            int4 bb = s_bb[f];
            hit = !((cy1 < bb.y) | (cy0 > bb.w) | (cx1 < bb.x) | (cx0 > bb.z));
        }
        unsigned long long m = __ballot(hit);
        if (hit) {
            int pos = __popcll(m & ((1ull << lane) - 1ull));
            s_list[wave * 128 + cnt + pos] = (short)f;
        }
        cnt += __popcll(m);
    }

    // ---- Phase B: survivors only ----
    const short* __restrict__ lst = &s_list[wave * 128];
    float acc = 0.f;
    int i = 0;
    for (; i + 2 <= cnt; i += 2) {
        int iA = lst[i] * 3, iB = lst[i + 1] * 3;
        float4 aA = s_cf[iA], bA = s_cf[iA + 1], cA = s_cf[iA + 2];
        float4 aB = s_cf[iB], bB = s_cf[iB + 1], cB = s_cf[iB + 2];
        float uA = fminf(fminf(fmaf(px, aA.x, fmaf(py, aA.y, aA.z)),
                               fmaf(px, bA.x, fmaf(py, bA.y, bA.z))),
                         fmaf(px, cA.x, fmaf(py, cA.y, cA.z)));
        float uB = fminf(fminf(fmaf(px, aB.x, fmaf(py, aB.y, aB.z)),
                               fmaf(px, bB.x, fmaf(py, bB.y, bB.z))),
                         fmaf(px, cB.x, fmaf(py, cB.y, cB.z)));
        acc += fmaxf(uA, 0.f) + fmaxf(uB, 0.f);
        float dA = fabsf(uA), dB = fabsf(uB);
        if (__any(fminf(dA, dB) < TCUT)) {  // far-lane corrections ~= 0 (exact-ish)
            acc += __builtin_amdgcn_logf(1.f + __builtin_amdgcn_exp2f(-dA)) +
                   __builtin_amdgcn_logf(1.f + __builtin_amdgcn_exp2f(-dB));
        }
        if (__all(acc > ACC_BREAK)) { i = cnt; break; }  // remaining < 2^-25
    }
    if (i < cnt) {  // tail (0 or 1 face)
        int iA = lst[i] * 3;
        float4 aA = s_cf[iA], bA = s_cf[iA + 1], cA = s_cf[iA + 2];
        float u = fminf(fminf(fmaf(px, aA.x, fmaf(py, aA.y, aA.z)),
                              fmaf(px, bA.x, fmaf(py, bA.y, bA.z))),
                        fmaf(px, cA.x, fmaf(py, cA.y, cA.z)));
        acc += fmaxf(u, 0.f);
        float d = fabsf(u);
        if (__any(d < TCUT)) {
            acc += __builtin_amdgcn_logf(1.f + __builtin_amdgcn_exp2f(-d));
        }
    }

    g_partial[chunk * (IMG * IMG) + row * IMG + col] = acc;
}

// ---------------------------------------------------------------------------
// Kernel 3: combine chunks, silhouette, squared error, row-mean reduce.
// ---------------------------------------------------------------------------
__global__ __launch_bounds__(256) void k_final(const float* __restrict__ image_ref,
                                               float* __restrict__ out) {
    const int row = blockIdx.x;
    const int col = threadIdx.x;
    const int pix = row * IMG + col;

    float ssum = 0.f;
#pragma unroll
    for (int c = 0; c < NCHUNK; ++c) ssum += g_partial[c * (IMG * IMG) + pix];

    float sil = 1.f - __builtin_amdgcn_exp2f(-ssum);
    float diff = sil - image_ref[pix];
    float v = diff * diff;

#pragma unroll
    for (int o = 32; o > 0; o >>= 1) v += __shfl_down(v, o);

    __shared__ float wsum[4];
    if ((col & 63) == 0) wsum[col >> 6] = v;
    __syncthreads();
    if (col == 0) {
        out[row] = (wsum[0] + wsum[1] + wsum[2] + wsum[3]) * (1.f / 256.f);
    }
}

// ---------------------------------------------------------------------------
extern "C" void kernel_launch(void* const* d_in, const int* in_sizes, int n_in,
                              void* d_out, int out_size, void* d_ws, size_t ws_size,
                              hipStream_t stream) {
    const float* verts = (const float*)d_in[0];      // (1,1000,3) f32
    const int* faces = (const int*)d_in[1];          // (1,1000,3) i32
    const float* q = (const float*)d_in[2];          // (4,) f32
    const float* t = (const float*)d_in[3];          // (3,) f32
    const float* K = (const float*)d_in[4];          // (3,3) f32
    const float* image_ref = (const float*)d_in[5];  // (256,256) f32
    float* out = (float*)d_out;                      // (256,) f32

    k_coeff<<<(NFACE + 255) / 256, 256, 0, stream>>>(verts, faces, q, t, K);
    k_partial<<<dim3(16, 16, NCHUNK), 256, 0, stream>>>();
    k_final<<<IMG, 256, 0, stream>>>(image_ref, out);
}

// Round 7
// 29.278 us; speedup vs baseline: 2.4471x; 1.5215x over previous
//
#include <hip/hip_runtime.h>
#include <math.h>

#define IMG 256
#define NFACE 1000
#define NCHUNK 8
#define FPC (NFACE / NCHUNK)   // 125 faces per chunk
#define EPSF 1e-8f
#define LOG2E 1.44269504088896f
#define TCUT 16.0f             // drop contributions with u < -TCUT (<= 1.44*2^-16 each)
#define ACC_BREAK 25.0f        // once all lanes exceed: sil error < 2^-25
// Tile-center cull: max_tile u <= min_k c_k(center) + 3.5*sqrt(2)*LOG2E (=7.15)
#define CULL_M (-(TCUT + 7.15f))

// Static device scratch (graph-capture safe).
// Per face: 3 x float4 = (cx, cy, c0, pad) per edge, pre-scaled by log2(e).
__device__ float4 g_cf[NFACE * 3];
__device__ float g_partial[NCHUNK * IMG * IMG];

// ---------------------------------------------------------------------------
// Kernel 1: per-face edge line coefficients, scaled by log2(e).
// No bbox: culling is done from the coefficients themselves (tile-center
// distance test), which handles sliver wedges and degenerate faces exactly.
// Degenerate (repeated-vertex) faces: zero edge -> c == 0 everywhere, other
// two edges are same line +/- normal -> u = -|dist|; the center test then
// keeps exactly the tiles within the band. No special case needed.
// ---------------------------------------------------------------------------
__global__ __launch_bounds__(256) void k_coeff(const float* __restrict__ verts,
                                               const int* __restrict__ faces,
                                               const float* __restrict__ q,
                                               const float* __restrict__ t,
                                               const float* __restrict__ K) {
    int f = blockIdx.x * blockDim.x + threadIdx.x;
    if (f >= NFACE) return;

    float qw = q[0], qx = q[1], qy = q[2], qz = q[3];
    float qn = sqrtf(qw * qw + qx * qx + qy * qy + qz * qz + EPSF);
    qw /= qn; qx /= qn; qy /= qn; qz /= qn;
    float R00 = 1.f - 2.f * (qy * qy + qz * qz);
    float R01 = 2.f * (qx * qy - qw * qz);
    float R02 = 2.f * (qx * qz + qw * qy);
    float R10 = 2.f * (qx * qy + qw * qz);
    float R11 = 1.f - 2.f * (qx * qx + qz * qz);
    float R12 = 2.f * (qy * qz - qw * qx);
    float R20 = 2.f * (qx * qz - qw * qy);
    float R21 = 2.f * (qy * qz + qw * qx);
    float R22 = 1.f - 2.f * (qx * qx + qy * qy);
    float tx = t[0], ty = t[1], tz = t[2];
    float K00 = K[0], K02 = K[2], K11 = K[4], K12 = K[5];

    float X[3], Y[3];
#pragma unroll
    for (int k = 0; k < 3; ++k) {
        int vi = faces[f * 3 + k];
        float vx = verts[vi * 3 + 0];
        float vy = verts[vi * 3 + 1];
        float vz = verts[vi * 3 + 2];
        float cx = R00 * vx + R01 * vy + R02 * vz + tx;
        float cy = R10 * vx + R11 * vy + R12 * vz + ty;
        float cz = R20 * vx + R21 * vy + R22 * vz + tz;
        float z = cz + EPSF;
        X[k] = K00 * cx / z + K02;
        Y[k] = K11 * cy / z + K12;
    }

    float e01x = X[1] - X[0], e01y = Y[1] - Y[0];
    float e02x = X[2] - X[0], e02y = Y[2] - Y[0];
    float area2 = e01x * e02y - e01y * e02x;
    float s = (area2 >= 0.f) ? LOG2E : -LOG2E;   // fold log2(e) into coeffs

    float4* dst = &g_cf[f * 3];
#pragma unroll
    for (int k = 0; k < 3; ++k) {
        int k1 = (k + 1) % 3;
        float ex = X[k1] - X[k];
        float ey = Y[k1] - Y[k];
        float inv = s / sqrtf(ex * ex + ey * ey + EPSF);
        dst[k] = make_float4(-ey * inv, ex * inv,
                             (ey * X[k] - ex * Y[k]) * inv, 0.f);
    }
}

// ---------------------------------------------------------------------------
// Kernel 2: heavy pass.
//   Stage:   chunk's 125 faces (3 x float4 each) -> LDS.
//   Phase A: tile-center line-distance cull (exact for bands/wedges/slivers):
//            lane l evaluates min3 of face l's edge functions at the wave's
//            8x8 tile center; keep iff > -(TCUT+7.15). Ballot-compact.
//   Phase B: survivors only, uniform LDS broadcast reads, 2-face unroll,
//            guarded transcendentals, every-2-faces early break.
// Grid: (16,16,NCHUNK) blocks of 256; wave = 8x8 px sub-tile.
// ---------------------------------------------------------------------------
__global__ __launch_bounds__(256) void k_partial() {
    const int chunk = blockIdx.z;
    const int tid = threadIdx.x;
    const int wave = tid >> 6;
    const int lane = tid & 63;

    const int cx0 = blockIdx.x * 16 + (wave & 1) * 8;
    const int cy0 = blockIdx.y * 16 + (wave >> 1) * 8;
    const int col = cx0 + (lane & 7);
    const int row = cy0 + (lane >> 3);
    const float px = col + 0.5f;
    const float py = row + 0.5f;
    const float tcx = cx0 + 4.0f;   // pixel centers span +0.5..+7.5
    const float tcy = cy0 + 4.0f;

    __shared__ float4 s_cf[FPC * 3];
    __shared__ short s_list[4 * 128];

    // ---- stage chunk faces into LDS ----
    const float4* __restrict__ src = &g_cf[chunk * FPC * 3];
    for (int j = tid; j < FPC * 3; j += 256) s_cf[j] = src[j];
    __syncthreads();

    // ---- Phase A: tile-center cull + compaction (per wave) ----
    int cnt = 0;
    for (int base = 0; base < FPC; base += 64) {
        int f = base + lane;
        bool hit = false;
        if (f < FPC) {
            float4 a = s_cf[f * 3], b = s_cf[f * 3 + 1], c = s_cf[f * 3 + 2];
            float m = fminf(fminf(fmaf(tcx, a.x, fmaf(tcy, a.y, a.z)),
                                  fmaf(tcx, b.x, fmaf(tcy, b.y, b.z))),
                            fmaf(tcx, c.x, fmaf(tcy, c.y, c.z)));
            hit = (m > CULL_M);
        }
        unsigned long long msk = __ballot(hit);
        if (hit) {
            int pos = __popcll(msk & ((1ull << lane) - 1ull));
            s_list[wave * 128 + cnt + pos] = (short)f;
        }
        cnt += __popcll(msk);
    }

    // ---- Phase B: survivors only ----
    const short* __restrict__ lst = &s_list[wave * 128];
    float acc = 0.f;
    int i = 0;
    for (; i + 2 <= cnt; i += 2) {
        int iA = lst[i] * 3, iB = lst[i + 1] * 3;
        float4 aA = s_cf[iA], bA = s_cf[iA + 1], cA = s_cf[iA + 2];
        float4 aB = s_cf[iB], bB = s_cf[iB + 1], cB = s_cf[iB + 2];
        float uA = fminf(fminf(fmaf(px, aA.x, fmaf(py, aA.y, aA.z)),
                               fmaf(px, bA.x, fmaf(py, bA.y, bA.z))),
                         fmaf(px, cA.x, fmaf(py, cA.y, cA.z)));
        float uB = fminf(fminf(fmaf(px, aB.x, fmaf(py, aB.y, aB.z)),
                               fmaf(px, bB.x, fmaf(py, bB.y, bB.z))),
                         fmaf(px, cB.x, fmaf(py, cB.y, cB.z)));
        acc += fmaxf(uA, 0.f) + fmaxf(uB, 0.f);
        float dA = fabsf(uA), dB = fabsf(uB);
        if (__any(fminf(dA, dB) < TCUT)) {  // far-lane corrections ~= 0
            acc += __builtin_amdgcn_logf(1.f + __builtin_amdgcn_exp2f(-dA)) +
                   __builtin_amdgcn_logf(1.f + __builtin_amdgcn_exp2f(-dB));
        }
        if (__all(acc > ACC_BREAK)) { i = cnt; break; }  // remaining < 2^-25
    }
    if (i < cnt) {  // tail (0 or 1 face)
        int iA = lst[i] * 3;
        float4 aA = s_cf[iA], bA = s_cf[iA + 1], cA = s_cf[iA + 2];
        float u = fminf(fminf(fmaf(px, aA.x, fmaf(py, aA.y, aA.z)),
                              fmaf(px, bA.x, fmaf(py, bA.y, bA.z))),
                        fmaf(px, cA.x, fmaf(py, cA.y, cA.z)));
        acc += fmaxf(u, 0.f);
        float d = fabsf(u);
        if (__any(d < TCUT)) {
            acc += __builtin_amdgcn_logf(1.f + __builtin_amdgcn_exp2f(-d));
        }
    }

    g_partial[chunk * (IMG * IMG) + row * IMG + col] = acc;
}

// ---------------------------------------------------------------------------
// Kernel 3: combine chunks, silhouette, squared error, row-mean reduce.
// ---------------------------------------------------------------------------
__global__ __launch_bounds__(256) void k_final(const float* __restrict__ image_ref,
                                               float* __restrict__ out) {
    const int row = blockIdx.x;
    const int col = threadIdx.x;
    const int pix = row * IMG + col;

    float ssum = 0.f;
#pragma unroll
    for (int c = 0; c < NCHUNK; ++c) ssum += g_partial[c * (IMG * IMG) + pix];

    float sil = 1.f - __builtin_amdgcn_exp2f(-ssum);
    float diff = sil - image_ref[pix];
    float v = diff * diff;

#pragma unroll
    for (int o = 32; o > 0; o >>= 1) v += __shfl_down(v, o);

    __shared__ float wsum[4];
    if ((col & 63) == 0) wsum[col >> 6] = v;
    __syncthreads();
    if (col == 0) {
        out[row] = (wsum[0] + wsum[1] + wsum[2] + wsum[3]) * (1.f / 256.f);
    }
}

// ---------------------------------------------------------------------------
extern "C" void kernel_launch(void* const* d_in, const int* in_sizes, int n_in,
                              void* d_out, int out_size, void* d_ws, size_t ws_size,
                              hipStream_t stream) {
    const float* verts = (const float*)d_in[0];      // (1,1000,3) f32
    const int* faces = (const int*)d_in[1];          // (1,1000,3) i32
    const float* q = (const float*)d_in[2];          // (4,) f32
    const float* t = (const float*)d_in[3];          // (3,) f32
    const float* K = (const float*)d_in[4];          // (3,3) f32
    const float* image_ref = (const float*)d_in[5];  // (256,256) f32
    float* out = (float*)d_out;                      // (256,) f32

    k_coeff<<<(NFACE + 255) / 256, 256, 0, stream>>>(verts, faces, q, t, K);
    k_partial<<<dim3(16, 16, NCHUNK), 256, 0, stream>>>();
    k_final<<<IMG, 256, 0, stream>>>(image_ref, out);
}

// Round 8
// 26.696 us; speedup vs baseline: 2.6837x; 1.0967x over previous
//
#include <hip/hip_runtime.h>
#include <math.h>

#define IMG 256
#define NFACE 1000
#define NWAVE 4
#define FPW 250                // faces per wave (NFACE / NWAVE)
#define EPSF 1e-8f
#define LOG2E 1.44269504088896f
#define TCUT 16.0f             // drop contributions with u < -TCUT (<= 1.44*2^-16 each)
#define ACC_BREAK 25.0f        // once all lanes of a wave exceed: its tail < 2^-25
// Tile-center cull: max_tile u <= min_k c_k(center) + 3.5*sqrt(2)*LOG2E (=7.15)
#define CULL_M (-(TCUT + 7.15f))

// Static device scratch (graph-capture safe).
// Per face: 3 x float4 = (cx, cy, c0, pad) per edge, pre-scaled by log2(e).
__device__ float4 g_cf[NFACE * 3];

// ---------------------------------------------------------------------------
// Kernel 1: per-face edge line coefficients (log2e-scaled). Block 0 also
// zeroes out[] for k_main's atomic row accumulation (stream-ordered).
// Degenerate faces (repeated vertex -> zero edge -> c==0 everywhere, face
// paints an infinite line band) need no special case under the center test.
// ---------------------------------------------------------------------------
__global__ __launch_bounds__(256) void k_coeff(const float* __restrict__ verts,
                                               const int* __restrict__ faces,
                                               const float* __restrict__ q,
                                               const float* __restrict__ t,
                                               const float* __restrict__ K,
                                               float* __restrict__ out) {
    if (blockIdx.x == 0 && threadIdx.x < IMG) out[threadIdx.x] = 0.f;

    int f = blockIdx.x * blockDim.x + threadIdx.x;
    if (f >= NFACE) return;

    float qw = q[0], qx = q[1], qy = q[2], qz = q[3];
    float qn = sqrtf(qw * qw + qx * qx + qy * qy + qz * qz + EPSF);
    qw /= qn; qx /= qn; qy /= qn; qz /= qn;
    float R00 = 1.f - 2.f * (qy * qy + qz * qz);
    float R01 = 2.f * (qx * qy - qw * qz);
    float R02 = 2.f * (qx * qz + qw * qy);
    float R10 = 2.f * (qx * qy + qw * qz);
    float R11 = 1.f - 2.f * (qx * qx + qz * qz);
    float R12 = 2.f * (qy * qz - qw * qx);
    float R20 = 2.f * (qx * qz - qw * qy);
    float R21 = 2.f * (qy * qz + qw * qx);
    float R22 = 1.f - 2.f * (qx * qx + qy * qy);
    float tx = t[0], ty = t[1], tz = t[2];
    float K00 = K[0], K02 = K[2], K11 = K[4], K12 = K[5];

    float X[3], Y[3];
#pragma unroll
    for (int k = 0; k < 3; ++k) {
        int vi = faces[f * 3 + k];
        float vx = verts[vi * 3 + 0];
        float vy = verts[vi * 3 + 1];
        float vz = verts[vi * 3 + 2];
        float cx = R00 * vx + R01 * vy + R02 * vz + tx;
        float cy = R10 * vx + R11 * vy + R12 * vz + ty;
        float cz = R20 * vx + R21 * vy + R22 * vz + tz;
        float z = cz + EPSF;
        X[k] = K00 * cx / z + K02;
        Y[k] = K11 * cy / z + K12;
    }

    float e01x = X[1] - X[0], e01y = Y[1] - Y[0];
    float e02x = X[2] - X[0], e02y = Y[2] - Y[0];
    float area2 = e01x * e02y - e01y * e02x;
    float s = (area2 >= 0.f) ? LOG2E : -LOG2E;   // fold log2(e) into coeffs

    float4* dst = &g_cf[f * 3];
#pragma unroll
    for (int k = 0; k < 3; ++k) {
        int k1 = (k + 1) % 3;
        float ex = X[k1] - X[k];
        float ey = Y[k1] - Y[k];
        float inv = s / sqrtf(ex * ex + ey * ey + EPSF);
        dst[k] = make_float4(-ey * inv, ex * inv,
                             (ey * X[k] - ex * Y[k]) * inv, 0.f);
    }
}

// ---------------------------------------------------------------------------
// Kernel 2: single-pass fused render+loss.
// Block = one 8x8 px tile, 4 waves; wave w handles faces [w*250,(w+1)*250):
//   Phase A: tile-center line-distance cull (4 ballot-compaction rounds,
//            coeffs read directly from L2 - no staging, no pre-cull sync).
//   Phase B: survivors only (uniform L1-hit reads, 2-face unroll, guarded
//            transcendentals, per-wave early break).
// Combine: 4 partial accs via LDS -> sil -> sqdiff -> 8-lane row reduce ->
//          atomicAdd row partial into out (zeroed by k_coeff).
// ---------------------------------------------------------------------------
__global__ __launch_bounds__(256) void k_main(const float* __restrict__ image_ref,
                                              float* __restrict__ out) {
    const int tid = threadIdx.x;
    const int wave = tid >> 6;
    const int lane = tid & 63;
    const int x0 = blockIdx.x * 8, y0 = blockIdx.y * 8;
    const int col = x0 + (lane & 7);
    const int row = y0 + (lane >> 3);
    const float px = col + 0.5f;
    const float py = row + 0.5f;
    const float tcx = x0 + 4.0f;   // pixel centers span +0.5..+7.5
    const float tcy = y0 + 4.0f;

    __shared__ short s_list[NWAVE][256];
    __shared__ float s_acc[NWAVE][64];

    // ---- Phase A: cull + compaction over this wave's 250 faces ----
    const int wbase = wave * FPW;
    int cnt = 0;
#pragma unroll
    for (int base = 0; base < FPW; base += 64) {
        int rel = base + lane;
        int f = wbase + rel;
        bool hit = false;
        if (rel < FPW) {
            const float4* __restrict__ cf = &g_cf[f * 3];
            float4 a = cf[0], b = cf[1], c = cf[2];
            float m = fminf(fminf(fmaf(tcx, a.x, fmaf(tcy, a.y, a.z)),
                                  fmaf(tcx, b.x, fmaf(tcy, b.y, b.z))),
                            fmaf(tcx, c.x, fmaf(tcy, c.y, c.z)));
            hit = (m > CULL_M);
        }
        unsigned long long msk = __ballot(hit);
        if (hit) {
            int pos = __popcll(msk & ((1ull << lane) - 1ull));
            s_list[wave][cnt + pos] = (short)f;
        }
        cnt += __popcll(msk);
    }

    // ---- Phase B: survivors only ----
    float acc = 0.f;
    int i = 0;
    for (; i + 2 <= cnt; i += 2) {
        int iA = s_list[wave][i] * 3, iB = s_list[wave][i + 1] * 3;
        float4 aA = g_cf[iA], bA = g_cf[iA + 1], cA = g_cf[iA + 2];
        float4 aB = g_cf[iB], bB = g_cf[iB + 1], cB = g_cf[iB + 2];
        float uA = fminf(fminf(fmaf(px, aA.x, fmaf(py, aA.y, aA.z)),
                               fmaf(px, bA.x, fmaf(py, bA.y, bA.z))),
                         fmaf(px, cA.x, fmaf(py, cA.y, cA.z)));
        float uB = fminf(fminf(fmaf(px, aB.x, fmaf(py, aB.y, aB.z)),
                               fmaf(px, bB.x, fmaf(py, bB.y, bB.z))),
                         fmaf(px, cB.x, fmaf(py, cB.y, cB.z)));
        acc += fmaxf(uA, 0.f) + fmaxf(uB, 0.f);
        float dA = fabsf(uA), dB = fabsf(uB);
        if (__any(fminf(dA, dB) < TCUT)) {  // far-lane corrections ~= 0
            acc += __builtin_amdgcn_logf(1.f + __builtin_amdgcn_exp2f(-dA)) +
                   __builtin_amdgcn_logf(1.f + __builtin_amdgcn_exp2f(-dB));
        }
        if (__all(acc > ACC_BREAK)) { i = cnt; break; }  // wave tail < 2^-25
    }
    if (i < cnt) {  // tail (0 or 1 face)
        int iA = s_list[wave][i] * 3;
        float4 aA = g_cf[iA], bA = g_cf[iA + 1], cA = g_cf[iA + 2];
        float u = fminf(fminf(fmaf(px, aA.x, fmaf(py, aA.y, aA.z)),
                              fmaf(px, bA.x, fmaf(py, bA.y, bA.z))),
                        fmaf(px, cA.x, fmaf(py, cA.y, cA.z)));
        acc += fmaxf(u, 0.f);
        float d = fabsf(u);
        if (__any(d < TCUT)) {
            acc += __builtin_amdgcn_logf(1.f + __builtin_amdgcn_exp2f(-d));
        }
    }

    // ---- combine waves, sil, sqdiff, row-reduce, atomic row partial ----
    s_acc[wave][lane] = acc;
    __syncthreads();
    if (wave == 0) {
        float tot = s_acc[0][lane] + s_acc[1][lane] +
                    s_acc[2][lane] + s_acc[3][lane];
        float sil = 1.f - __builtin_amdgcn_exp2f(-tot);
        float d = sil - image_ref[row * IMG + col];
        float v = d * d;
        v += __shfl_xor(v, 1);   // lanes r*8+c: sum over c (one tile row)
        v += __shfl_xor(v, 2);
        v += __shfl_xor(v, 4);
        if ((lane & 7) == 0) atomicAdd(&out[row], v * (1.f / 256.f));
    }
}

// ---------------------------------------------------------------------------
extern "C" void kernel_launch(void* const* d_in, const int* in_sizes, int n_in,
                              void* d_out, int out_size, void* d_ws, size_t ws_size,
                              hipStream_t stream) {
    const float* verts = (const float*)d_in[0];      // (1,1000,3) f32
    const int* faces = (const int*)d_in[1];          // (1,1000,3) i32
    const float* q = (const float*)d_in[2];          // (4,) f32
    const float* t = (const float*)d_in[3];          // (3,) f32
    const float* K = (const float*)d_in[4];          // (3,3) f32
    const float* image_ref = (const float*)d_in[5];  // (256,256) f32
    float* out = (float*)d_out;                      // (256,) f32

    k_coeff<<<(NFACE + 255) / 256, 256, 0, stream>>>(verts, faces, q, t, K, out);
    k_main<<<dim3(IMG / 8, IMG / 8), 256, 0, stream>>>(image_ref, out);
}

// Round 9
// 24.444 us; speedup vs baseline: 2.9310x; 1.0921x over previous
//
#include <hip/hip_runtime.h>
#include <math.h>

#define IMG 256
#define NFACE 1000
#define NFP 1024               // padded face count (per-wave 256, 4 rounds of 64)
#define NWAVE 4
#define EPSF 1e-8f
#define LOG2E 1.44269504088896f
#define TCUT 16.0f             // drop contributions with u < -TCUT (<= 1.44*2^-16 each)
#define ACC_BREAK 25.0f        // once all lanes of a wave exceed: its tail < 2^-25
// Tile-center cull: max_tile u <= min_k c_k(center) + 3.5*sqrt(2)*LOG2E (=7.15)
#define CULL_M (-(TCUT + 7.15f))

// Static device scratch (graph-capture safe).
// SoA for the cull pass (coalesced dword loads), AoS float4 for the compute
// pass (uniform broadcast loads). Both log2e-scaled. Faces >= NFACE are
// self-rejecting pads (c = -1e9): never survive cull, contribute exactly 0.
__device__ float g_soa[9][NFP];
__device__ float4 g_cf[NFP * 3];

// ---------------------------------------------------------------------------
// Kernel 1: per-face edge line coefficients (log2e-scaled), SoA + AoS.
// Also zeroes out[] (block 0) for k_main's atomic row accumulation.
// Degenerate faces (repeated vertex -> zero edge -> c==0 everywhere) need no
// special case under the center-distance cull.
// ---------------------------------------------------------------------------
__global__ __launch_bounds__(256) void k_coeff(const float* __restrict__ verts,
                                               const int* __restrict__ faces,
                                               const float* __restrict__ q,
                                               const float* __restrict__ t,
                                               const float* __restrict__ K,
                                               float* __restrict__ out) {
    int f = blockIdx.x * 256 + threadIdx.x;   // grid = 4 blocks -> f in [0,1024)
    if (blockIdx.x == 0 && threadIdx.x < IMG) out[threadIdx.x] = 0.f;
    if (f >= NFP) return;

    float c[9];
    if (f < NFACE) {
        float qw = q[0], qx = q[1], qy = q[2], qz = q[3];
        float qn = sqrtf(qw * qw + qx * qx + qy * qy + qz * qz + EPSF);
        qw /= qn; qx /= qn; qy /= qn; qz /= qn;
        float R00 = 1.f - 2.f * (qy * qy + qz * qz);
        float R01 = 2.f * (qx * qy - qw * qz);
        float R02 = 2.f * (qx * qz + qw * qy);
        float R10 = 2.f * (qx * qy + qw * qz);
        float R11 = 1.f - 2.f * (qx * qx + qz * qz);
        float R12 = 2.f * (qy * qz - qw * qx);
        float R20 = 2.f * (qx * qz - qw * qy);
        float R21 = 2.f * (qy * qz + qw * qx);
        float R22 = 1.f - 2.f * (qx * qx + qy * qy);
        float tx = t[0], ty = t[1], tz = t[2];
        float K00 = K[0], K02 = K[2], K11 = K[4], K12 = K[5];

        float X[3], Y[3];
#pragma unroll
        for (int k = 0; k < 3; ++k) {
            int vi = faces[f * 3 + k];
            float vx = verts[vi * 3 + 0];
            float vy = verts[vi * 3 + 1];
            float vz = verts[vi * 3 + 2];
            float cx = R00 * vx + R01 * vy + R02 * vz + tx;
            float cy = R10 * vx + R11 * vy + R12 * vz + ty;
            float cz = R20 * vx + R21 * vy + R22 * vz + tz;
            float z = cz + EPSF;
            X[k] = K00 * cx / z + K02;
            Y[k] = K11 * cy / z + K12;
        }

        float e01x = X[1] - X[0], e01y = Y[1] - Y[0];
        float e02x = X[2] - X[0], e02y = Y[2] - Y[0];
        float area2 = e01x * e02y - e01y * e02x;
        float s = (area2 >= 0.f) ? LOG2E : -LOG2E;   // fold log2(e) in

#pragma unroll
        for (int k = 0; k < 3; ++k) {
            int k1 = (k + 1) % 3;
            float ex = X[k1] - X[k];
            float ey = Y[k1] - Y[k];
            float inv = s / sqrtf(ex * ex + ey * ey + EPSF);
            c[k * 3 + 0] = -ey * inv;
            c[k * 3 + 1] = ex * inv;
            c[k * 3 + 2] = (ey * X[k] - ex * Y[k]) * inv;
        }
    } else {
        // self-rejecting pad / zero-contribution sentinel
        c[0] = 0.f; c[1] = 0.f; c[2] = -1e9f;
        c[3] = 0.f; c[4] = 0.f; c[5] = -1e9f;
        c[6] = 0.f; c[7] = 0.f; c[8] = -1e9f;
    }

#pragma unroll
    for (int k = 0; k < 9; ++k) g_soa[k][f] = c[k];
    g_cf[f * 3 + 0] = make_float4(c[0], c[1], c[2], 0.f);
    g_cf[f * 3 + 1] = make_float4(c[3], c[4], c[5], 0.f);
    g_cf[f * 3 + 2] = make_float4(c[6], c[7], c[8], 0.f);
}

// ---------------------------------------------------------------------------
// Kernel 2: fused render+loss. Block = 8x8 px tile, 4 waves; wave w owns
// faces [w*256, (w+1)*256) (pads self-reject).
//   Phase A: tile-center cull, SoA coalesced dword loads, 4 ballot-compaction
//            rounds, survivor list padded to x4 with sentinel face NFACE.
//   Phase B: 4-face unrolled walk (short4 index fetch, uniform AoS broadcast
//            loads, unconditional transcendentals, break-check per group).
// Combine: LDS wave-acc sum -> sil -> sqdiff -> 8-lane row reduce ->
//          atomicAdd row partials into out.
// ---------------------------------------------------------------------------
__global__ __launch_bounds__(256) void k_main(const float* __restrict__ image_ref,
                                              float* __restrict__ out) {
    const int tid = threadIdx.x;
    const int wave = tid >> 6;
    const int lane = tid & 63;
    const int x0 = blockIdx.x * 8, y0 = blockIdx.y * 8;
    const int col = x0 + (lane & 7);
    const int row = y0 + (lane >> 3);
    const float px = col + 0.5f;
    const float py = row + 0.5f;
    const float tcx = x0 + 4.0f;   // pixel centers span +0.5..+7.5
    const float tcy = y0 + 4.0f;

    __shared__ __align__(8) short s_list[NWAVE][260];
    __shared__ float s_acc[NWAVE][64];

    // ---- Phase A: cull + compaction (4 rounds, no bounds checks) ----
    const int wbase = wave * 256;
    int cnt = 0;
#pragma unroll
    for (int r = 0; r < 4; ++r) {
        int f = wbase + r * 64 + lane;
        float a0 = g_soa[0][f], a1 = g_soa[1][f], a2 = g_soa[2][f];
        float b0 = g_soa[3][f], b1 = g_soa[4][f], b2 = g_soa[5][f];
        float d0 = g_soa[6][f], d1 = g_soa[7][f], d2 = g_soa[8][f];
        float m = fminf(fminf(fmaf(tcx, a0, fmaf(tcy, a1, a2)),
                              fmaf(tcx, b0, fmaf(tcy, b1, b2))),
                        fmaf(tcx, d0, fmaf(tcy, d1, d2)));
        bool hit = (m > CULL_M);
        unsigned long long msk = __ballot(hit);
        if (hit) {
            int pos = __popcll(msk & ((1ull << lane) - 1ull));
            s_list[wave][cnt + pos] = (short)f;
        }
        cnt += __popcll(msk);
    }
    // pad survivor list to a multiple of 4 with the zero-contribution sentinel
    int cntp = (cnt + 3) & ~3;
    if (lane < cntp - cnt) s_list[wave][cnt + lane] = (short)NFACE;

    // ---- Phase B: survivors, 4-face groups ----
    float acc = 0.f;
    for (int i = 0; i < cntp; i += 4) {
        short4 id = *(const short4*)&s_list[wave][i];
        const float4* pA = &g_cf[id.x * 3];
        const float4* pB = &g_cf[id.y * 3];
        const float4* pC = &g_cf[id.z * 3];
        const float4* pD = &g_cf[id.w * 3];
        float4 aA = pA[0], bA = pA[1], cA = pA[2];
        float4 aB = pB[0], bB = pB[1], cB = pB[2];
        float4 aC = pC[0], bC = pC[1], cC = pC[2];
        float4 aD = pD[0], bD = pD[1], cD = pD[2];
        float uA = fminf(fminf(fmaf(px, aA.x, fmaf(py, aA.y, aA.z)),
                               fmaf(px, bA.x, fmaf(py, bA.y, bA.z))),
                         fmaf(px, cA.x, fmaf(py, cA.y, cA.z)));
        float uB = fminf(fminf(fmaf(px, aB.x, fmaf(py, aB.y, aB.z)),
                               fmaf(px, bB.x, fmaf(py, bB.y, bB.z))),
                         fmaf(px, cB.x, fmaf(py, cB.y, cB.z)));
        float uC = fminf(fminf(fmaf(px, aC.x, fmaf(py, aC.y, aC.z)),
                               fmaf(px, bC.x, fmaf(py, bC.y, bC.z))),
                         fmaf(px, cC.x, fmaf(py, cC.y, cC.z)));
        float uD = fminf(fminf(fmaf(px, aD.x, fmaf(py, aD.y, aD.z)),
                               fmaf(px, bD.x, fmaf(py, bD.y, bD.z))),
                         fmaf(px, cD.x, fmaf(py, cD.y, cD.z)));
        acc += fmaxf(uA, 0.f) + fmaxf(uB, 0.f) + fmaxf(uC, 0.f) + fmaxf(uD, 0.f);
        acc += __builtin_amdgcn_logf(1.f + __builtin_amdgcn_exp2f(-fabsf(uA)));
        acc += __builtin_amdgcn_logf(1.f + __builtin_amdgcn_exp2f(-fabsf(uB)));
        acc += __builtin_amdgcn_logf(1.f + __builtin_amdgcn_exp2f(-fabsf(uC)));
        acc += __builtin_amdgcn_logf(1.f + __builtin_amdgcn_exp2f(-fabsf(uD)));
        if (__all(acc > ACC_BREAK)) break;   // wave's remaining tail < 2^-25
    }

    // ---- combine waves, sil, sqdiff, row-reduce, atomic row partial ----
    s_acc[wave][lane] = acc;
    __syncthreads();
    if (wave == 0) {
        float tot = s_acc[0][lane] + s_acc[1][lane] +
                    s_acc[2][lane] + s_acc[3][lane];
        float sil = 1.f - __builtin_amdgcn_exp2f(-tot);
        float d = sil - image_ref[row * IMG + col];
        float v = d * d;
        v += __shfl_xor(v, 1);   // sum over the 8 cols of this tile row
        v += __shfl_xor(v, 2);
        v += __shfl_xor(v, 4);
        if ((lane & 7) == 0) atomicAdd(&out[row], v * (1.f / 256.f));
    }
}

// ---------------------------------------------------------------------------
extern "C" void kernel_launch(void* const* d_in, const int* in_sizes, int n_in,
                              void* d_out, int out_size, void* d_ws, size_t ws_size,
                              hipStream_t stream) {
    const float* verts = (const float*)d_in[0];      // (1,1000,3) f32
    const int* faces = (const int*)d_in[1];          // (1,1000,3) i32
    const float* q = (const float*)d_in[2];          // (4,) f32
    const float* t = (const float*)d_in[3];          // (3,) f32
    const float* K = (const float*)d_in[4];          // (3,3) f32
    const float* image_ref = (const float*)d_in[5];  // (256,256) f32
    float* out = (float*)d_out;                      // (256,) f32

    k_coeff<<<NFP / 256, 256, 0, stream>>>(verts, faces, q, t, K, out);
    k_main<<<dim3(IMG / 8, IMG / 8), 256, 0, stream>>>(image_ref, out);
}